// Round 2
// baseline (3915.874 us; speedup 1.0000x reference)
//
#include <hip/hip_runtime.h>
#include <hip/hip_bf16.h>
#include <math.h>

// Problem constants
#define D_MODEL 768
#define D_INNER 1536
#define D_STATE 16
#define D_CONV  4
#define DT_RANK 48
#define BB      4
#define LL      2048
#define MROWS   (BB*LL)          // 8192
#define D2      (2*D_INNER)      // 3072
#define XD      (DT_RANK + 2*D_STATE) // 80

// ---------------- LayerNorm (+ residual copy to out) ----------------
__global__ __launch_bounds__(256) void ln_kernel(const float* __restrict__ x,
    const float* __restrict__ g, const float* __restrict__ b,
    float* __restrict__ xn, float* __restrict__ out)
{
    int row = blockIdx.x;
    int tid = threadIdx.x;
    const float* xr = x + (size_t)row * D_MODEL;
    float v0 = xr[tid], v1 = xr[tid + 256], v2 = xr[tid + 512];
    float s = v0 + v1 + v2;
    float s2 = v0*v0 + v1*v1 + v2*v2;
    for (int off = 32; off; off >>= 1) {
        s  += __shfl_down(s, off);
        s2 += __shfl_down(s2, off);
    }
    __shared__ float sh[8];
    int lane = tid & 63, wid = tid >> 6;
    if (lane == 0) { sh[wid] = s; sh[wid + 4] = s2; }
    __syncthreads();
    if (tid == 0) {
        float S  = sh[0] + sh[1] + sh[2] + sh[3];
        float S2 = sh[4] + sh[5] + sh[6] + sh[7];
        float mu = S * (1.f / D_MODEL);
        float var = S2 * (1.f / D_MODEL) - mu * mu;
        sh[0] = mu;
        sh[1] = rsqrtf(var + 1e-5f);
    }
    __syncthreads();
    float mu = sh[0], rstd = sh[1];
    float* xnr  = xn  + (size_t)row * D_MODEL;
    float* outr = out + (size_t)row * D_MODEL;
#pragma unroll
    for (int j = 0; j < 3; ++j) {
        int i = tid + j * 256;
        float v = xr[i];
        xnr[i]  = (v - mu) * rstd * g[i] + b[i];
        outr[i] = v;
    }
}

// ---------------- Generic NT GEMM: C[M,N] = A[M,K(lda)] * W[N,K]^T ----------------
// epi: 0 = plain store; 1 = softplus(acc + bias[n]) store; 2 = accumulate into C
// rev:      remap A row (b,t) -> (b, L-1-t) on load
// revstore: remap C row (b,t) -> (b, L-1-t) on store (for epi==2 backward dir)
__global__ __launch_bounds__(256) void gemm_nt(const float* __restrict__ A, int lda,
    const float* __restrict__ W, float* __restrict__ C,
    int M, int N, int K, const float* __restrict__ bias, int epi, int rev, int revstore)
{
    __shared__ float As[16][68];
    __shared__ float Ws[16][68];
    int tid = threadIdx.x;
    int m0 = blockIdx.x * 64;
    int n0 = blockIdx.y * 64;
    int tx = tid & 15, ty = tid >> 4;
    int lrow = tid >> 2;
    int lk4  = (tid & 3) << 2;

    int arow = m0 + lrow;
    if (rev) arow = (arow & ~(LL - 1)) | ((LL - 1) - (arow & (LL - 1)));
    const float* ap = A + (size_t)arow * lda + lk4;
    int wrow = n0 + lrow;
    const float* wp = (wrow < N) ? (W + (size_t)wrow * K + lk4) : nullptr;

    float acc[4][4] = {{0.f}};

    for (int k0 = 0; k0 < K; k0 += 16) {
        float4 av = *(const float4*)(ap + k0);
        float4 wv = wp ? *(const float4*)(wp + k0) : make_float4(0.f, 0.f, 0.f, 0.f);
        __syncthreads();
        As[lk4 + 0][lrow] = av.x; As[lk4 + 1][lrow] = av.y;
        As[lk4 + 2][lrow] = av.z; As[lk4 + 3][lrow] = av.w;
        Ws[lk4 + 0][lrow] = wv.x; Ws[lk4 + 1][lrow] = wv.y;
        Ws[lk4 + 2][lrow] = wv.z; Ws[lk4 + 3][lrow] = wv.w;
        __syncthreads();
#pragma unroll
        for (int k = 0; k < 16; ++k) {
            float4 a4 = *(const float4*)&As[k][ty << 2];
            float4 w4 = *(const float4*)&Ws[k][tx << 2];
            float ar[4] = {a4.x, a4.y, a4.z, a4.w};
            float wr[4] = {w4.x, w4.y, w4.z, w4.w};
#pragma unroll
            for (int i = 0; i < 4; ++i)
#pragma unroll
                for (int j = 0; j < 4; ++j)
                    acc[i][j] += ar[i] * wr[j];
        }
    }

#pragma unroll
    for (int i = 0; i < 4; ++i) {
        int m = m0 + (ty << 2) + i;
        int mout = m;
        if (revstore) mout = (m & ~(LL - 1)) | ((LL - 1) - (m & (LL - 1)));
        float* cr = C + (size_t)mout * N;
#pragma unroll
        for (int j = 0; j < 4; ++j) {
            int n = n0 + (tx << 2) + j;
            if (n < N) {
                float v = acc[i][j];
                if (epi == 1) {
                    v += bias[n];
                    v = fmaxf(v, 0.f) + log1pf(__expf(-fabsf(v)));
                    cr[n] = v;
                } else if (epi == 2) {
                    cr[n] += v;
                } else {
                    cr[n] = v;
                }
            }
        }
    }
}

// ---------------- Causal depthwise conv (k=4) + silu ----------------
__global__ __launch_bounds__(256) void conv_silu_kernel(const float* __restrict__ xz,
    const float* __restrict__ cw, const float* __restrict__ cb, float* __restrict__ xc)
{
    int idx = blockIdx.x * 256 + threadIdx.x;   // over MROWS*D_INNER
    int d = idx % D_INNER;
    int m = idx / D_INNER;
    int t = m & (LL - 1);
    const float* base = xz + (size_t)m * D2 + d;
    float w0 = cw[d * 4 + 0], w1 = cw[d * 4 + 1], w2 = cw[d * 4 + 2], w3 = cw[d * 4 + 3];
    float acc = cb[d] + w3 * base[0];
    if (t >= 1) acc += w2 * base[-(size_t)D2];
    if (t >= 2) acc += w1 * base[-(size_t)(2 * D2)];
    if (t >= 3) acc += w0 * base[-(size_t)(3 * D2)];
    xc[idx] = acc / (1.f + __expf(-acc));
}

// ---------------- Selective scan: 16 lanes per (b,d) channel ----------------
// y may alias dt (in-place): all 16 lanes read dt[base] before lane 0 stores
// y[base] (same wave, program order) and each channel is owned by one group.
__global__ __launch_bounds__(256) void scan_kernel(const float* __restrict__ dt,
    const float* __restrict__ xc, const float* __restrict__ xdbl,
    const float* __restrict__ Alog, float* __restrict__ y)
{
    int tid = threadIdx.x;
    int s = tid & 15;
    int ch = blockIdx.x * 16 + (tid >> 4);   // 0..6143
    int b = ch / D_INNER, d = ch % D_INNER;
    float A = -__expf(Alog[d * D_STATE + s]);
    size_t base   = (size_t)b * LL * D_INNER + d;
    size_t base80 = (size_t)b * LL * XD;
    float h = 0.f;
    for (int t = 0; t < LL; ++t) {
        float dtv = dt[base];
        float xv  = xc[base];
        float Bv  = xdbl[base80 + DT_RANK + s];
        float Cv  = xdbl[base80 + DT_RANK + D_STATE + s];
        float dA = __expf(dtv * A);
        h = dA * h + (dtv * xv) * Bv;
        float p = h * Cv;
        p += __shfl_xor(p, 1);
        p += __shfl_xor(p, 2);
        p += __shfl_xor(p, 4);
        p += __shfl_xor(p, 8);
        if (s == 0) y[base] = p;
        base += D_INNER;
        base80 += XD;
    }
}

// ---------------- y = (y + D*xc) * silu(z), in-place on y ----------------
__global__ __launch_bounds__(256) void elemwise_kernel(float* __restrict__ y,
    const float* __restrict__ xc, const float* __restrict__ xz, const float* __restrict__ Dp)
{
    int idx = blockIdx.x * 256 + threadIdx.x;   // over MROWS*D_INNER
    int d = idx % D_INNER;
    int m = idx / D_INNER;
    float z = xz[(size_t)m * D2 + D_INNER + d];
    float v = (y[idx] + Dp[d] * xc[idx]) * (z / (1.f + __expf(-z)));
    y[idx] = v;
}

extern "C" void kernel_launch(void* const* d_in, const int* in_sizes, int n_in,
                              void* d_out, int out_size, void* d_ws, size_t ws_size,
                              hipStream_t stream) {
    const float* x    = (const float*)d_in[0];
    const float* ln_g = (const float*)d_in[1];
    const float* ln_b = (const float*)d_in[2];

    // Workspace layout (fp32), total 57.27M floats = 229.1 MB:
    float* ws = (float*)d_ws;
    float* xn   = ws;                                   // 8192*768
    float* xz   = xn   + (size_t)MROWS * D_MODEL;       // 8192*3072
    float* xc   = xz   + (size_t)MROWS * D2;            // 8192*1536
    float* xdbl = xc   + (size_t)MROWS * D_INNER;       // 8192*80
    float* dtb  = xdbl + (size_t)MROWS * XD;            // 8192*1536 (dt, then y in-place)

    float* out = (float*)d_out;

    ln_kernel<<<MROWS, 256, 0, stream>>>(x, ln_g, ln_b, xn, out);

    for (int dir = 0; dir < 2; ++dir) {
        int o = 3 + dir * 9;
        const float* Win   = (const float*)d_in[o + 0];
        const float* convw = (const float*)d_in[o + 1];
        const float* convb = (const float*)d_in[o + 2];
        const float* Wx    = (const float*)d_in[o + 3];
        const float* Wdt   = (const float*)d_in[o + 4];
        const float* bdt   = (const float*)d_in[o + 5];
        const float* Alog  = (const float*)d_in[o + 6];
        const float* Dp    = (const float*)d_in[o + 7];
        const float* Wout  = (const float*)d_in[o + 8];
        int rev = dir;

        // xz = xn(rev?) @ Win^T   [8192 x 3072]
        gemm_nt<<<dim3(MROWS / 64, D2 / 64), 256, 0, stream>>>(
            xn, D_MODEL, Win, xz, MROWS, D2, D_MODEL, nullptr, 0, rev, 0);
        // xc = silu(conv(xz[:, :1536]))
        conv_silu_kernel<<<(MROWS * D_INNER) / 256, 256, 0, stream>>>(xz, convw, convb, xc);
        // xdbl = xc @ Wx^T   [8192 x 80]
        gemm_nt<<<dim3(MROWS / 64, 2), 256, 0, stream>>>(
            xc, D_INNER, Wx, xdbl, MROWS, XD, D_INNER, nullptr, 0, 0, 0);
        // dt = softplus(xdbl[:, :48] @ Wdt^T + bdt)   [8192 x 1536]
        gemm_nt<<<dim3(MROWS / 64, D_INNER / 64), 256, 0, stream>>>(
            xdbl, XD, Wdt, dtb, MROWS, D_INNER, DT_RANK, bdt, 1, 0, 0);
        // selective scan -> y in-place into dtb
        scan_kernel<<<(BB * D_INNER) / 16, 256, 0, stream>>>(dtb, xc, xdbl, Alog, dtb);
        // y = (y + D*xc) * silu(z), in-place
        elemwise_kernel<<<(MROWS * D_INNER) / 256, 256, 0, stream>>>(dtb, xc, xz, Dp);
        // out += (y @ Wout^T), rows reversed on store for backward dir
        gemm_nt<<<dim3(MROWS / 64, D_MODEL / 64), 256, 0, stream>>>(
            dtb, D_INNER, Wout, out, MROWS, D_MODEL, D_INNER, nullptr, 2, 0, rev);
    }
}

// Round 3
// 3185.554 us; speedup vs baseline: 1.2293x; 1.2293x over previous
//
#include <hip/hip_runtime.h>
#include <hip/hip_bf16.h>
#include <math.h>

// Problem constants
#define D_MODEL 768
#define D_INNER 1536
#define D_STATE 16
#define D_CONV  4
#define DT_RANK 48
#define BB      4
#define LL      2048
#define MROWS   (BB*LL)          // 8192
#define D2      (2*D_INNER)      // 3072
#define XD      (DT_RANK + 2*D_STATE) // 80

// ---------------- LayerNorm (+ residual copy to out) ----------------
__global__ __launch_bounds__(256) void ln_kernel(const float* __restrict__ x,
    const float* __restrict__ g, const float* __restrict__ b,
    float* __restrict__ xn, float* __restrict__ out)
{
    int row = blockIdx.x;
    int tid = threadIdx.x;
    const float* xr = x + (size_t)row * D_MODEL;
    float v0 = xr[tid], v1 = xr[tid + 256], v2 = xr[tid + 512];
    float s = v0 + v1 + v2;
    float s2 = v0*v0 + v1*v1 + v2*v2;
    for (int off = 32; off; off >>= 1) {
        s  += __shfl_down(s, off);
        s2 += __shfl_down(s2, off);
    }
    __shared__ float sh[8];
    int lane = tid & 63, wid = tid >> 6;
    if (lane == 0) { sh[wid] = s; sh[wid + 4] = s2; }
    __syncthreads();
    if (tid == 0) {
        float S  = sh[0] + sh[1] + sh[2] + sh[3];
        float S2 = sh[4] + sh[5] + sh[6] + sh[7];
        float mu = S * (1.f / D_MODEL);
        float var = S2 * (1.f / D_MODEL) - mu * mu;
        sh[0] = mu;
        sh[1] = rsqrtf(var + 1e-5f);
    }
    __syncthreads();
    float mu = sh[0], rstd = sh[1];
    float* xnr  = xn  + (size_t)row * D_MODEL;
    float* outr = out + (size_t)row * D_MODEL;
#pragma unroll
    for (int j = 0; j < 3; ++j) {
        int i = tid + j * 256;
        float v = xr[i];
        xnr[i]  = (v - mu) * rstd * g[i] + b[i];
        outr[i] = v;
    }
}

// ---------------- Generic NT GEMM: C[M,N] = A[M,K(lda)] * W[N,K]^T ----------------
// epi: 0 = plain store; 1 = softplus(acc + bias[n]) store; 2 = accumulate into C
// rev:      remap A row (b,t) -> (b, L-1-t) on load
// revstore: remap C row (b,t) -> (b, L-1-t) on store (for epi==2 backward dir)
__global__ __launch_bounds__(256) void gemm_nt(const float* __restrict__ A, int lda,
    const float* __restrict__ W, float* __restrict__ C,
    int M, int N, int K, const float* __restrict__ bias, int epi, int rev, int revstore)
{
    __shared__ float As[16][68];
    __shared__ float Ws[16][68];
    int tid = threadIdx.x;
    int m0 = blockIdx.x * 64;
    int n0 = blockIdx.y * 64;
    int tx = tid & 15, ty = tid >> 4;
    int lrow = tid >> 2;
    int lk4  = (tid & 3) << 2;

    int arow = m0 + lrow;
    if (rev) arow = (arow & ~(LL - 1)) | ((LL - 1) - (arow & (LL - 1)));
    const float* ap = A + (size_t)arow * lda + lk4;
    int wrow = n0 + lrow;
    const float* wp = (wrow < N) ? (W + (size_t)wrow * K + lk4) : nullptr;

    float acc[4][4] = {{0.f}};

    for (int k0 = 0; k0 < K; k0 += 16) {
        float4 av = *(const float4*)(ap + k0);
        float4 wv = wp ? *(const float4*)(wp + k0) : make_float4(0.f, 0.f, 0.f, 0.f);
        __syncthreads();
        As[lk4 + 0][lrow] = av.x; As[lk4 + 1][lrow] = av.y;
        As[lk4 + 2][lrow] = av.z; As[lk4 + 3][lrow] = av.w;
        Ws[lk4 + 0][lrow] = wv.x; Ws[lk4 + 1][lrow] = wv.y;
        Ws[lk4 + 2][lrow] = wv.z; Ws[lk4 + 3][lrow] = wv.w;
        __syncthreads();
#pragma unroll
        for (int k = 0; k < 16; ++k) {
            float4 a4 = *(const float4*)&As[k][ty << 2];
            float4 w4 = *(const float4*)&Ws[k][tx << 2];
            float ar[4] = {a4.x, a4.y, a4.z, a4.w};
            float wr[4] = {w4.x, w4.y, w4.z, w4.w};
#pragma unroll
            for (int i = 0; i < 4; ++i)
#pragma unroll
                for (int j = 0; j < 4; ++j)
                    acc[i][j] += ar[i] * wr[j];
        }
    }

#pragma unroll
    for (int i = 0; i < 4; ++i) {
        int m = m0 + (ty << 2) + i;
        int mout = m;
        if (revstore) mout = (m & ~(LL - 1)) | ((LL - 1) - (m & (LL - 1)));
        float* cr = C + (size_t)mout * N;
#pragma unroll
        for (int j = 0; j < 4; ++j) {
            int n = n0 + (tx << 2) + j;
            if (n < N) {
                float v = acc[i][j];
                if (epi == 1) {
                    v += bias[n];
                    v = fmaxf(v, 0.f) + log1pf(__expf(-fabsf(v)));
                    cr[n] = v;
                } else if (epi == 2) {
                    cr[n] += v;
                } else {
                    cr[n] = v;
                }
            }
        }
    }
}

// ---------------- Causal depthwise conv (k=4) + silu ----------------
__global__ __launch_bounds__(256) void conv_silu_kernel(const float* __restrict__ xz,
    const float* __restrict__ cw, const float* __restrict__ cb, float* __restrict__ xc)
{
    int idx = blockIdx.x * 256 + threadIdx.x;   // over MROWS*D_INNER
    int d = idx % D_INNER;
    int m = idx / D_INNER;
    int t = m & (LL - 1);
    const float* base = xz + (size_t)m * D2 + d;
    float w0 = cw[d * 4 + 0], w1 = cw[d * 4 + 1], w2 = cw[d * 4 + 2], w3 = cw[d * 4 + 3];
    float acc = cb[d] + w3 * base[0];
    if (t >= 1) acc += w2 * base[-(size_t)D2];
    if (t >= 2) acc += w1 * base[-(size_t)(2 * D2)];
    if (t >= 3) acc += w0 * base[-(size_t)(3 * D2)];
    xc[idx] = acc / (1.f + __expf(-acc));
}

// ---------------- Selective scan, software-pipelined, fused elemwise ----------------
// 16 lanes per (b,d) channel; unroll-by-4 with one-block-deep prefetch so the
// loop-carried chain is just h = dA*h + u. Lane 0 applies the
// (p + D*xc)*silu(z) epilogue and stores the final y (in-place over dt).
#define SU 4
__global__ __launch_bounds__(256) void scan_kernel(const float* __restrict__ dt,
    const float* __restrict__ xc, const float* __restrict__ xdbl,
    const float* __restrict__ Alog, const float* __restrict__ xz,
    const float* __restrict__ Dp, float* __restrict__ y)
{
    int tid = threadIdx.x;
    int s = tid & 15;
    int ch = blockIdx.x * 16 + (tid >> 4);   // 0..6143
    int b = ch / D_INNER, d = ch % D_INNER;
    float A  = -__expf(Alog[d * D_STATE + s]);
    float Dv = Dp[d];
    size_t base   = (size_t)b * LL * D_INNER + d;
    size_t baseZ  = (size_t)b * LL * D2 + D_INNER + d;
    size_t base80 = (size_t)b * LL * XD + DT_RANK + s;

    float p_dt[SU], p_x[SU], p_B[SU], p_C[SU], p_z[SU];
#pragma unroll
    for (int i = 0; i < SU; ++i) {
        p_dt[i] = dt[base + (size_t)i * D_INNER];
        p_x[i]  = xc[base + (size_t)i * D_INNER];
        p_B[i]  = xdbl[base80 + (size_t)i * XD];
        p_C[i]  = xdbl[base80 + (size_t)i * XD + D_STATE];
        p_z[i]  = xz[baseZ + (size_t)i * D2];
    }

    float h = 0.f;
    for (int t0 = 0; t0 < LL; t0 += SU) {
        float c_dt[SU], c_x[SU], c_B[SU], c_C[SU], c_z[SU];
#pragma unroll
        for (int i = 0; i < SU; ++i) {
            c_dt[i] = p_dt[i]; c_x[i] = p_x[i]; c_B[i] = p_B[i];
            c_C[i] = p_C[i];   c_z[i] = p_z[i];
        }
        // prefetch next block (wraps to t=0 on the last iter; values unused)
        int tn = (t0 + SU < LL) ? (t0 + SU) : 0;
        size_t nb  = base   + (size_t)tn * D_INNER;
        size_t nb8 = base80 + (size_t)tn * XD;
        size_t nbz = baseZ  + (size_t)tn * D2;
#pragma unroll
        for (int i = 0; i < SU; ++i) {
            p_dt[i] = dt[nb + (size_t)i * D_INNER];
            p_x[i]  = xc[nb + (size_t)i * D_INNER];
            p_B[i]  = xdbl[nb8 + (size_t)i * XD];
            p_C[i]  = xdbl[nb8 + (size_t)i * XD + D_STATE];
            p_z[i]  = xz[nbz + (size_t)i * D2];
        }
#pragma unroll
        for (int i = 0; i < SU; ++i) {
            float dA = __expf(c_dt[i] * A);
            h = fmaf(dA, h, (c_dt[i] * c_x[i]) * c_B[i]);
            float p = h * c_C[i];
            p += __shfl_xor(p, 1);
            p += __shfl_xor(p, 2);
            p += __shfl_xor(p, 4);
            p += __shfl_xor(p, 8);
            if (s == 0) {
                float z = c_z[i];
                float v = (p + Dv * c_x[i]) * (z / (1.f + __expf(-z)));
                y[base + (size_t)(t0 + i) * D_INNER] = v;
            }
        }
    }
}

extern "C" void kernel_launch(void* const* d_in, const int* in_sizes, int n_in,
                              void* d_out, int out_size, void* d_ws, size_t ws_size,
                              hipStream_t stream) {
    const float* x    = (const float*)d_in[0];
    const float* ln_g = (const float*)d_in[1];
    const float* ln_b = (const float*)d_in[2];

    // Workspace layout (fp32), total ~229 MB:
    float* ws = (float*)d_ws;
    float* xn   = ws;                                   // 8192*768
    float* xz   = xn   + (size_t)MROWS * D_MODEL;       // 8192*3072
    float* xc   = xz   + (size_t)MROWS * D2;            // 8192*1536
    float* xdbl = xc   + (size_t)MROWS * D_INNER;       // 8192*80
    float* dtb  = xdbl + (size_t)MROWS * XD;            // 8192*1536 (dt, then y in-place)

    float* out = (float*)d_out;

    ln_kernel<<<MROWS, 256, 0, stream>>>(x, ln_g, ln_b, xn, out);

    for (int dir = 0; dir < 2; ++dir) {
        int o = 3 + dir * 9;
        const float* Win   = (const float*)d_in[o + 0];
        const float* convw = (const float*)d_in[o + 1];
        const float* convb = (const float*)d_in[o + 2];
        const float* Wx    = (const float*)d_in[o + 3];
        const float* Wdt   = (const float*)d_in[o + 4];
        const float* bdt   = (const float*)d_in[o + 5];
        const float* Alog  = (const float*)d_in[o + 6];
        const float* Dp    = (const float*)d_in[o + 7];
        const float* Wout  = (const float*)d_in[o + 8];
        int rev = dir;

        // xz = xn(rev?) @ Win^T   [8192 x 3072]
        gemm_nt<<<dim3(MROWS / 64, D2 / 64), 256, 0, stream>>>(
            xn, D_MODEL, Win, xz, MROWS, D2, D_MODEL, nullptr, 0, rev, 0);
        // xc = silu(conv(xz[:, :1536]))
        conv_silu_kernel<<<(MROWS * D_INNER) / 256, 256, 0, stream>>>(xz, convw, convb, xc);
        // xdbl = xc @ Wx^T   [8192 x 80]
        gemm_nt<<<dim3(MROWS / 64, 2), 256, 0, stream>>>(
            xc, D_INNER, Wx, xdbl, MROWS, XD, D_INNER, nullptr, 0, 0, 0);
        // dt = softplus(xdbl[:, :48] @ Wdt^T + bdt)   [8192 x 1536]
        gemm_nt<<<dim3(MROWS / 64, D_INNER / 64), 256, 0, stream>>>(
            xdbl, XD, Wdt, dtb, MROWS, D_INNER, DT_RANK, bdt, 1, 0, 0);
        // selective scan + fused (p + D*xc)*silu(z), y in-place into dtb
        scan_kernel<<<(BB * D_INNER) / 16, 256, 0, stream>>>(
            dtb, xc, xdbl, Alog, xz, Dp, dtb);
        // out += (y @ Wout^T), rows reversed on store for backward dir
        gemm_nt<<<dim3(MROWS / 64, D_MODEL / 64), 256, 0, stream>>>(
            dtb, D_INNER, Wout, out, MROWS, D_MODEL, D_INNER, nullptr, 2, 0, rev);
    }
}